// Round 1
// baseline (101.167 us; speedup 1.0000x reference)
//
#include <hip/hip_runtime.h>

// NEAT windowed-DAG forward, 4-lanes-per-element version.
//   values[0:16] = x; for i in 0..511: v = tanh(dot(values[i:i+16], w[i]) + b[i]) * r[i]
//   out = values[T-64:T]
//
// R7: the R6 kernel was latency-bound at 1 wave/SIMD on half the SIMDs
// (Occupancy 4.3%, VALUBusy 22%, 198 cyc/node vs ~48 cyc of issue). Split
// each batch element across a DPP quad: lane j holds window positions
// 4j..4j+3; per node: 4 fmas + 2-stage quad_perm DPP reduce + redundant
// sigmoid chain + 1-register window migration (quad_perm[1,2,3,0] +
// cndmask inserting the new output at lane 3). 2048 waves = 2 waves/SIMD
// on all 4 SIMDs -> TLP hides the serial chain and DS latency.
//
// t-domain transform: carry t = tanh(z) instead of v = r*t. Weights are
// pre-scaled at staging by kScale * r_src (r=1 for input sources), so the
// per-node metadata is just b*kScale (one float). LDS stream: per 4-node
// quad = 4 per-lane weight b128 + 1 replicated-bias b128 -> the proven
// counted pipeline (5 reads/set, 4 rotating sets, lgkmcnt(15)) carries
// over with 12 nodes of slack. Outputs multiply r back in at store time.

typedef float v4f __attribute__((ext_vector_type(4)));

constexpr int kNOut     = 64;
constexpr int kBatch    = 32768;
constexpr int kQStrideF = 80;                       // floats per quad block (320 B)
constexpr int kLdsFloats = (128 + 3) * kQStrideF;   // 128 quads + 3 pad (prefetch overrun)
constexpr float kScale  = 2.8853900817779268f;      // 2*log2(e)

// quad_perm DPP through the builtin so the compiler handles hazard nops.
#define QPERM(X, CTRL) __int_as_float(__builtin_amdgcn_update_dpp(            \
    __float_as_int(X), __float_as_int(X), (CTRL), 0xF, 0xF, false))

// Issue the 5 ds_read_b128 for quad S: per-lane weights of nodes c=0..3 at
// byte offsets c*64 (+ lane j*16 already folded into `a`), plus the
// 4-way-replicated bias block at +256 (lane j reads replica j -> identical
// data, distinct banks). Earlyclobber: dests must not alias the addr reg.
#define PREFQ(S) {                                                            \
    asm volatile(                                                             \
      "ds_read_b128 %0, %5 offset:0\n\t"                                      \
      "ds_read_b128 %1, %5 offset:64\n\t"                                     \
      "ds_read_b128 %2, %5 offset:128\n\t"                                    \
      "ds_read_b128 %3, %5 offset:192\n\t"                                    \
      "ds_read_b128 %4, %5 offset:256"                                        \
      : "=&v"(qw0[S]), "=&v"(qw1[S]), "=&v"(qw2[S]), "=&v"(qw3[S]),           \
        "=&v"(qb[S])                                                          \
      : "v"(a));                                                              \
    a += kQStrideF * 4; }

// After PREFQ of quad Q+3, the 15 newer reads (quads Q+1..Q+3) may remain
// outstanding; in-order DS returns make lgkmcnt(15) == "set Q landed".
// Nothing else in the loop touches lgkmcnt, so the count is exact.
#define WAITQ(S)                                                              \
    asm volatile("s_waitcnt lgkmcnt(15)"                                      \
      : "+v"(qw0[S]), "+v"(qw1[S]), "+v"(qw2[S]), "+v"(qw3[S]), "+v"(qb[S]));

// One node. WA..WD = lane's window quarter (WD = newest; lane3's WD is the
// previous node's output -> final fma is the only op on the serial chain).
// Bias enters once via lane0's fma init (off-chain cndmask). Reduce:
// s1 = p + p(lane^1); sf = s1 + s1(lane^2) == ((p0+p1)+(p2+p3)) — same
// association as R6. Migration: lane j's vacated reg gets lane j+1's WA
// (quad_perm[1,2,3,0]); lane 3 gets the new output.
#define NODE1(QW, BSV, WA, WB, WC, WD) {                                      \
    float ini = is_l0 ? (BSV) : 0.0f;                                         \
    float p = fmaf((WA), (QW).x, ini);                                        \
    p = fmaf((WB), (QW).y, p);                                                \
    p = fmaf((WC), (QW).z, p);                                                \
    p = fmaf((WD), (QW).w, p);                                                \
    float s1 = p + QPERM(p, 0xB1);          /* quad_perm:[1,0,3,2] */         \
    float sf = s1 + QPERM(s1, 0x4E);        /* quad_perm:[2,3,0,1] */         \
    float ex = __builtin_amdgcn_exp2f(sf);                                    \
    float uu = __builtin_amdgcn_rcpf(ex + 1.0f);                              \
    float tn = fmaf(-2.0f, uu, 1.0f);       /* t = 1 - 2*sigmoid(-2z) */      \
    float mg = QPERM((WA), 0x39);           /* quad_perm:[1,2,3,0] */         \
    (WA) = is_l3 ? tn : mg; }

// Quad of nodes: prefetch quad S+3, wait for quad S, run 4 nodes with the
// window names rotating (period 4 -> names return to r0..r3 after each quad).
#define NODEQ(S) {                                                            \
    PREFQ(((S) + 3) & 3)                                                      \
    WAITQ(S)                                                                  \
    v4f f0 = qw0[S], f1 = qw1[S], f2 = qw2[S], f3 = qw3[S], fb = qb[S];       \
    NODE1(f0, fb.x, r0, r1, r2, r3)                                           \
    NODE1(f1, fb.y, r1, r2, r3, r0)                                           \
    NODE1(f2, fb.z, r2, r3, r0, r1)                                           \
    NODE1(f3, fb.w, r3, r0, r1, r2) }

__global__ __launch_bounds__(512) void neat_fwd(
    const float* __restrict__ x,      // [B, 16]
    const float* __restrict__ w,      // [512, 16]
    const float* __restrict__ bias,   // [512]
    const float* __restrict__ resp,   // [512]
    float* __restrict__ out)          // [B, 64]
{
    __shared__ alignas(16) float ldsw[kLdsFloats];
    __shared__ float rst[512];

    const int t  = threadIdx.x;       // 0..511 (8 waves)
    const int jl = t & 3;             // lane within quad
    const bool is_l0 = (jl == 0);
    const bool is_l3 = (jl == 3);

    // ---- Stage: raw resp, then t-domain weights w' = w*kScale*r_src ----
    rst[t] = resp[t];
    __syncthreads();

    const float4* __restrict__ w4 = reinterpret_cast<const float4*>(w);
    #pragma unroll
    for (int k = 0; k < 4; ++k) {
        int i4 = t + k * 512;                 // [0, 2048) float4s of w
        float4 v = w4[i4];
        int n = i4 >> 2, k4 = i4 & 3;
        int s0 = n + 4 * k4;                  // global src idx of component .x
        float f0 = kScale * ((s0 + 0 < 16) ? 1.0f : rst[s0 - 16]);
        float f1 = kScale * ((s0 + 1 < 16) ? 1.0f : rst[s0 - 15]);
        float f2 = kScale * ((s0 + 2 < 16) ? 1.0f : rst[s0 - 14]);
        float f3 = kScale * ((s0 + 3 < 16) ? 1.0f : rst[s0 - 13]);
        float4 sc = make_float4(v.x * f0, v.y * f1, v.z * f2, v.w * f3);
        *reinterpret_cast<float4*>(
            &ldsw[(n >> 2) * kQStrideF + (n & 3) * 16 + k4 * 4]) = sc;
    }
    {   // bias block: 4 replicas of (b[4Q]..b[4Q+3])*kScale at quad offset +256B
        float bs = bias[t] * kScale;
        int q = t >> 2, s = t & 3;
        #pragma unroll
        for (int rep = 0; rep < 4; ++rep)
            ldsw[q * kQStrideF + 64 + rep * 4 + s] = bs;
    }

    // ---- Per-thread state: window quarter + output r-vectors ----
    const int e = blockIdx.x * 128 + (t >> 2);     // batch element
    const float4 xi = reinterpret_cast<const float4*>(x)[e * 4 + jl];
    float r0 = xi.x, r1 = xi.y, r2 = xi.z, r3 = xi.w;   // positions 4j..4j+3

    // resp for output nodes 448..511: rvK[c] = resp[448 + 16K + 4*jl + c]
    const float4* __restrict__ rr4 = reinterpret_cast<const float4*>(resp);
    const float4 rv0 = rr4[112 + jl], rv1 = rr4[116 + jl],
                 rv2 = rr4[120 + jl], rv3 = rr4[124 + jl];

    float* __restrict__ op = out + (size_t)e * kNOut + jl * 4;

    __syncthreads();   // drains staging ds ops (compiler lgkmcnt(0))

    // DS byte address cursor (+ lane's j*16 weight offset folded in).
    unsigned int a = (unsigned int)(unsigned long long)(&ldsw[0])
                   + (unsigned int)(jl << 4);

    v4f qw0[4], qw1[4], qw2[4], qw3[4], qb[4];
    PREFQ(0) PREFQ(1) PREFQ(2)     // quads 0,1,2 in flight

    #pragma unroll 1
    for (int g = 0; g < 32; ++g) {
        NODEQ(0) NODEQ(1) NODEQ(2) NODEQ(3)
        // After the group, lane jl's r0..r3 = t-values of nodes 16g+4jl+{0..3}.
        if (g >= 28) {
            float4 rv = (g == 28) ? rv0 : (g == 29) ? rv1
                      : (g == 30) ? rv2 : rv3;
            *reinterpret_cast<float4*>(op + (g - 28) * 16) =
                make_float4(r0 * rv.x, r1 * rv.y, r2 * rv.z, r3 * rv.w);
        }
    }

    // Drain overrun prefetches (pad quads 128..130).
    asm volatile("s_waitcnt lgkmcnt(0)" ::: "memory");
}

extern "C" void kernel_launch(void* const* d_in, const int* in_sizes, int n_in,
                              void* d_out, int out_size, void* d_ws, size_t ws_size,
                              hipStream_t stream) {
    const float* x    = (const float*)d_in[0];
    const float* w    = (const float*)d_in[1];
    const float* bias = (const float*)d_in[2];
    const float* resp = (const float*)d_in[3];
    float* out = (float*)d_out;
    // in_sizes[4] (src_idx) encodes the fixed windowed topology; hardcoded above.
    dim3 block(512);
    dim3 grid((kBatch * 4) / 512);   // 256 blocks -> 1 per CU, 8 waves/CU
    hipLaunchKernelGGL(neat_fwd, grid, block, 0, stream, x, w, bias, resp, out);
}